// Round 1
// baseline (2388.372 us; speedup 1.0000x reference)
//
#include <hip/hip_runtime.h>
#include <hip/hip_bf16.h>

static constexpr int NINP = 128;
static constexpr int D2   = 256;

// ---------------- graph build ----------------

__global__ void init_deg_kernel(int* __restrict__ deg, int n) {
    int i = blockIdx.x * blockDim.x + threadIdx.x;
    if (i < n) deg[i] = 0;
}

__global__ void count_kernel(const int* __restrict__ dst, int* __restrict__ deg, int E) {
    int e = blockIdx.x * blockDim.x + threadIdx.x;
    if (e < E) atomicAdd(&deg[dst[e]], 1);
}

__global__ void dinv_kernel(const int* __restrict__ deg, float* __restrict__ dinv, int n) {
    int i = blockIdx.x * blockDim.x + threadIdx.x;
    if (i < n) dinv[i] = rsqrtf((float)deg[i] + 1.0f);
}

__global__ __launch_bounds__(1024) void scan_kernel(const int* __restrict__ deg,
                                                    int* __restrict__ row_start,
                                                    int* __restrict__ cursor, int n) {
    __shared__ int lds[1024];
    int t = threadIdx.x;
    int chunk = (n + 1023) >> 10;
    int beg = t * chunk, end = min(beg + chunk, n);
    int s = 0;
    for (int i = beg; i < end; ++i) s += deg[i];
    lds[t] = s;
    __syncthreads();
    for (int off = 1; off < 1024; off <<= 1) {
        int v = (t >= off) ? lds[t - off] : 0;
        __syncthreads();
        lds[t] += v;
        __syncthreads();
    }
    int run = lds[t] - s;  // exclusive prefix
    for (int i = beg; i < end; ++i) {
        row_start[i] = run;
        cursor[i] = run;
        run += deg[i];
    }
    if (t == 1023) row_start[n] = lds[1023];
}

__global__ void fill_csr_kernel(const int* __restrict__ src, const int* __restrict__ dst,
                                const float* __restrict__ dinv, int* __restrict__ cursor,
                                int* __restrict__ csr_src, float* __restrict__ csr_w, int E) {
    int e = blockIdx.x * blockDim.x + threadIdx.x;
    if (e < E) {
        int s = src[e], d = dst[e];
        int pos = atomicAdd(&cursor[d], 1);
        csr_src[pos] = s;
        csr_w[pos] = dinv[s] * dinv[d];
    }
}

// ---------------- fp32 GEMM: C[M,N] = A[M,K] @ B[K,N], row-major ----------------
// BM=128, BN=64, BK=16, 256 threads, 8x4 micro-tile.

__global__ __launch_bounds__(256) void gemm_kernel(const float* __restrict__ A,
                                                   const float* __restrict__ B,
                                                   float* __restrict__ C,
                                                   int M, int K, int N) {
    __shared__ float As[16][132];  // [k][m], padded
    __shared__ float Bs[16][68];   // [k][n], padded
    int tid = threadIdx.x;
    int tx = tid & 15, ty = tid >> 4;
    int bm = blockIdx.x * 128, bn = blockIdx.y * 64;
    float acc[8][4] = {};

    int ar  = tid >> 2;          // 0..63 (two A rows: ar, ar+64)
    int ac4 = (tid & 3) * 4;     // k within tile
    int br  = tid >> 4;          // 0..15 (B k-row)
    int bc4 = (tid & 15) * 4;    // n within tile
    int arow0 = bm + ar, arow1 = bm + ar + 64;

    for (int k0 = 0; k0 < K; k0 += 16) {
        float4 av0 = make_float4(0.f, 0.f, 0.f, 0.f);
        float4 av1 = make_float4(0.f, 0.f, 0.f, 0.f);
        if (arow0 < M) av0 = *reinterpret_cast<const float4*>(A + (size_t)arow0 * K + k0 + ac4);
        if (arow1 < M) av1 = *reinterpret_cast<const float4*>(A + (size_t)arow1 * K + k0 + ac4);
        float4 bv = *reinterpret_cast<const float4*>(B + (size_t)(k0 + br) * N + bn + bc4);
        __syncthreads();
        As[ac4 + 0][ar] = av0.x; As[ac4 + 1][ar] = av0.y;
        As[ac4 + 2][ar] = av0.z; As[ac4 + 3][ar] = av0.w;
        As[ac4 + 0][ar + 64] = av1.x; As[ac4 + 1][ar + 64] = av1.y;
        As[ac4 + 2][ar + 64] = av1.z; As[ac4 + 3][ar + 64] = av1.w;
        *reinterpret_cast<float4*>(&Bs[br][bc4]) = bv;
        __syncthreads();
#pragma unroll
        for (int k = 0; k < 16; ++k) {
            float a[8], b[4];
            *reinterpret_cast<float4*>(&a[0]) = *reinterpret_cast<const float4*>(&As[k][ty * 8]);
            *reinterpret_cast<float4*>(&a[4]) = *reinterpret_cast<const float4*>(&As[k][ty * 8 + 4]);
            *reinterpret_cast<float4*>(&b[0]) = *reinterpret_cast<const float4*>(&Bs[k][tx * 4]);
#pragma unroll
            for (int i = 0; i < 8; ++i)
#pragma unroll
                for (int j = 0; j < 4; ++j) acc[i][j] += a[i] * b[j];
        }
    }
#pragma unroll
    for (int i = 0; i < 8; ++i) {
        int row = bm + ty * 8 + i;
        if (row < M) {
            float4 v = make_float4(acc[i][0], acc[i][1], acc[i][2], acc[i][3]);
            *reinterpret_cast<float4*>(C + (size_t)row * N + bn + tx * 4) = v;
        }
    }
}

// ---------------- aggregation: out[i] = sum_e w_e*H[src_e] + dinv2[i]*H[i] + b (+epi) ----------------
// one 64-lane wave per node. VEC=4 -> F=256 (float4/lane), VEC=2 -> F=128 (float2/lane).
// EPI: 0 = bias only, 1 = bias + l2norm, 2 = bias + residual add (Zadd)

template <int VEC, int EPI>
__global__ __launch_bounds__(256) void agg_kernel(const float* __restrict__ H,
                                                  const float* __restrict__ bias,
                                                  const float* __restrict__ Zadd,
                                                  const int* __restrict__ row_start,
                                                  const int* __restrict__ csr_src,
                                                  const float* __restrict__ csr_w,
                                                  const float* __restrict__ dinv,
                                                  float* __restrict__ out, int n) {
    const int F = VEC * 64;
    int lane = threadIdx.x & 63;
    int node = blockIdx.x * 4 + (threadIdx.x >> 6);
    if (node >= n) return;

    float acc[VEC];
    float di = dinv[node];
    float d2 = di * di;
    {
        const float* hp = H + (size_t)node * F + lane * VEC;
        if constexpr (VEC == 4) {
            float4 hv = *reinterpret_cast<const float4*>(hp);
            acc[0] = d2 * hv.x; acc[1] = d2 * hv.y; acc[2] = d2 * hv.z; acc[3] = d2 * hv.w;
        } else {
            float2 hv = *reinterpret_cast<const float2*>(hp);
            acc[0] = d2 * hv.x; acc[1] = d2 * hv.y;
        }
    }
    int beg = row_start[node], end = row_start[node + 1];
    for (int e = beg; e < end; ++e) {
        int s = csr_src[e];
        float w = csr_w[e];
        const float* hp = H + (size_t)s * F + lane * VEC;
        if constexpr (VEC == 4) {
            float4 hv = *reinterpret_cast<const float4*>(hp);
            acc[0] += w * hv.x; acc[1] += w * hv.y; acc[2] += w * hv.z; acc[3] += w * hv.w;
        } else {
            float2 hv = *reinterpret_cast<const float2*>(hp);
            acc[0] += w * hv.x; acc[1] += w * hv.y;
        }
    }
#pragma unroll
    for (int v = 0; v < VEC; ++v) acc[v] += bias[lane * VEC + v];

    if constexpr (EPI == 1) {
        float ss = 0.f;
#pragma unroll
        for (int v = 0; v < VEC; ++v) ss += acc[v] * acc[v];
#pragma unroll
        for (int off = 32; off; off >>= 1) ss += __shfl_xor(ss, off);
        float scale = 1.0f / fmaxf(sqrtf(ss), 1e-12f);
#pragma unroll
        for (int v = 0; v < VEC; ++v) acc[v] *= scale;
    } else if constexpr (EPI == 2) {
        const float* zp = Zadd + (size_t)node * F + lane * VEC;
#pragma unroll
        for (int v = 0; v < VEC; ++v) acc[v] += zp[v];
    }

    float* op = out + (size_t)node * F + lane * VEC;
    if constexpr (VEC == 4) {
        *reinterpret_cast<float4*>(op) = make_float4(acc[0], acc[1], acc[2], acc[3]);
    } else {
        *reinterpret_cast<float2*>(op) = make_float2(acc[0], acc[1]);
    }
}

// ---------------- RK4 combine: ACC (+)= ca*K [init from X0]; XT = X0 + cx*K ----------------

__global__ __launch_bounds__(256) void comb_kernel(const float4* __restrict__ X0,
                                                   const float4* __restrict__ Kv,
                                                   float4* __restrict__ ACC,
                                                   float4* __restrict__ XT,
                                                   float ca, float cx, int accInit,
                                                   int writeXT, int n4) {
    int i = blockIdx.x * 256 + threadIdx.x;
    if (i >= n4) return;
    float4 k = Kv[i];
    float4 x0 = X0[i];
    float4 a = accInit ? x0 : ACC[i];
    a.x += ca * k.x; a.y += ca * k.y; a.z += ca * k.z; a.w += ca * k.w;
    ACC[i] = a;
    if (writeXT) {
        float4 t;
        t.x = x0.x + cx * k.x; t.y = x0.y + cx * k.y;
        t.z = x0.z + cx * k.z; t.w = x0.w + cx * k.w;
        XT[i] = t;
    }
}

// ---------------- launch ----------------

extern "C" void kernel_launch(void* const* d_in, const int* in_sizes, int n_in,
                              void* d_out, int out_size, void* d_ws, size_t ws_size,
                              hipStream_t stream) {
    const float* emb = (const float*)d_in[0];
    const int* ei    = (const int*)d_in[1];
    const float* W1  = (const float*)d_in[2];
    const float* b1  = (const float*)d_in[3];
    const float* Wf1 = (const float*)d_in[4];
    const float* bf1 = (const float*)d_in[5];
    const float* Wf2 = (const float*)d_in[6];
    const float* bf2 = (const float*)d_in[7];
    const float* W2  = (const float*)d_in[8];
    const float* b2  = (const float*)d_in[9];
    float* out = (float*)d_out;

    const int N = in_sizes[0] / NINP;  // 50000
    const int E = in_sizes[1] / 2;     // 800000
    const int* esrc = ei;
    const int* edst = ei + E;

    char* p = (char*)d_ws;
    auto alloc = [&](size_t bytes) -> char* {
        char* r = p;
        p += (bytes + 255) & ~(size_t)255;
        return r;
    };
    int*   deg       = (int*)alloc((size_t)N * 4);
    float* dinv      = (float*)alloc((size_t)N * 4);
    int*   row_start = (int*)alloc((size_t)(N + 1) * 4);
    int*   cursor    = (int*)alloc((size_t)N * 4);
    int*   csr_src   = (int*)alloc((size_t)E * 4);
    float* csr_w     = (float*)alloc((size_t)E * 4);
    float* H   = (float*)alloc((size_t)N * D2 * 4);
    float* X0  = (float*)alloc((size_t)N * D2 * 4);
    float* Z1  = (float*)alloc((size_t)N * D2 * 4);  // also holds k
    float* XT  = (float*)alloc((size_t)N * D2 * 4);
    float* ACC = (float*)alloc((size_t)N * D2 * 4);

    const int gN = (N + 255) / 256, gE = (E + 255) / 256;
    init_deg_kernel<<<gN, 256, 0, stream>>>(deg, N);
    count_kernel<<<gE, 256, 0, stream>>>(edst, deg, E);
    dinv_kernel<<<gN, 256, 0, stream>>>(deg, dinv, N);
    scan_kernel<<<1, 1024, 0, stream>>>(deg, row_start, cursor, N);
    fill_csr_kernel<<<gE, 256, 0, stream>>>(esrc, edst, dinv, cursor, csr_src, csr_w, E);

    auto gemm = [&](const float* A, const float* B, float* C, int K, int Ncols) {
        dim3 grid((N + 127) / 128, Ncols / 64);
        gemm_kernel<<<grid, 256, 0, stream>>>(A, B, C, N, K, Ncols);
    };
    const int gAgg = (N + 3) / 4;
    const int n4 = N * D2 / 4;
    const int gC = (n4 + 255) / 256;

    // conv1 + l2norm -> X0
    gemm(emb, W1, H, NINP, D2);
    agg_kernel<4, 1><<<gAgg, 256, 0, stream>>>(H, b1, nullptr, row_start, csr_src, csr_w, dinv, X0, N);

    // f(z) -> writes result into Z1 (Z1 used internally as temp first)
    auto fcall = [&](const float* z) {
        gemm(z, Wf1, H, D2, D2);
        agg_kernel<4, 1><<<gAgg, 256, 0, stream>>>(H, bf1, nullptr, row_start, csr_src, csr_w, dinv, Z1, N);
        gemm(Z1, Wf2, H, D2, D2);
        agg_kernel<4, 2><<<gAgg, 256, 0, stream>>>(H, bf2, z, row_start, csr_src, csr_w, dinv, Z1, N);
    };

    // k1
    fcall(X0);
    comb_kernel<<<gC, 256, 0, stream>>>((const float4*)X0, (const float4*)Z1, (float4*)ACC, (float4*)XT,
                                        1.f / 6.f, 0.5f, 1, 1, n4);
    // k2
    fcall(XT);
    comb_kernel<<<gC, 256, 0, stream>>>((const float4*)X0, (const float4*)Z1, (float4*)ACC, (float4*)XT,
                                        1.f / 3.f, 0.5f, 0, 1, n4);
    // k3
    fcall(XT);
    comb_kernel<<<gC, 256, 0, stream>>>((const float4*)X0, (const float4*)Z1, (float4*)ACC, (float4*)XT,
                                        1.f / 3.f, 1.0f, 0, 1, n4);
    // k4
    fcall(XT);
    comb_kernel<<<gC, 256, 0, stream>>>((const float4*)X0, (const float4*)Z1, (float4*)ACC, (float4*)XT,
                                        1.f / 6.f, 0.0f, 0, 0, n4);

    // final conv -> d_out
    gemm(ACC, W2, H, D2, NINP);
    agg_kernel<2, 0><<<gAgg, 256, 0, stream>>>(H, b2, nullptr, row_start, csr_src, csr_w, dinv, out, N);
}

// Round 3
// 1945.078 us; speedup vs baseline: 1.2279x; 1.2279x over previous
//
#include <hip/hip_runtime.h>
#include <hip/hip_bf16.h>

static constexpr int NINP = 128;
static constexpr int D2   = 256;

using u16 = unsigned short;
using u32 = unsigned int;

typedef __attribute__((ext_vector_type(8))) __bf16 bf16x8;
typedef __attribute__((ext_vector_type(4))) float f32x4;

__device__ __forceinline__ u16 f2bf(float f) {
    union { float f; u32 u; } v;
    v.f = f;
    u32 u = v.u + 0x7fff + ((v.u >> 16) & 1);  // RNE
    return (u16)(u >> 16);
}
__device__ __forceinline__ u32 pack2(float a, float b) {
    return (u32)f2bf(a) | ((u32)f2bf(b) << 16);
}

// ---------------- graph build (round-1 verbatim) ----------------

__global__ void init_deg_kernel(int* __restrict__ deg, int n) {
    int i = blockIdx.x * blockDim.x + threadIdx.x;
    if (i < n) deg[i] = 0;
}

__global__ void count_kernel(const int* __restrict__ dst, int* __restrict__ deg, int E) {
    int e = blockIdx.x * blockDim.x + threadIdx.x;
    if (e < E) atomicAdd(&deg[dst[e]], 1);
}

__global__ void dinv_kernel(const int* __restrict__ deg, float* __restrict__ dinv, int n) {
    int i = blockIdx.x * blockDim.x + threadIdx.x;
    if (i < n) dinv[i] = rsqrtf((float)deg[i] + 1.0f);
}

__global__ __launch_bounds__(1024) void scan_kernel(const int* __restrict__ deg,
                                                    int* __restrict__ row_start,
                                                    int* __restrict__ cursor, int n) {
    __shared__ int lds[1024];
    int t = threadIdx.x;
    int chunk = (n + 1023) >> 10;
    int beg = t * chunk, end = min(beg + chunk, n);
    int s = 0;
    for (int i = beg; i < end; ++i) s += deg[i];
    lds[t] = s;
    __syncthreads();
    for (int off = 1; off < 1024; off <<= 1) {
        int v = (t >= off) ? lds[t - off] : 0;
        __syncthreads();
        lds[t] += v;
        __syncthreads();
    }
    int run = lds[t] - s;  // exclusive prefix
    for (int i = beg; i < end; ++i) {
        row_start[i] = run;
        cursor[i] = run;
        run += deg[i];
    }
    if (t == 1023) row_start[n] = lds[1023];
}

__global__ void fill_csr_kernel(const int* __restrict__ src, const int* __restrict__ dst,
                                const float* __restrict__ dinv, int* __restrict__ cursor,
                                int* __restrict__ csr_src, float* __restrict__ csr_w, int E) {
    int e = blockIdx.x * blockDim.x + threadIdx.x;
    if (e < E) {
        int s = src[e], d = dst[e];
        int pos = atomicAdd(&cursor[d], 1);
        csr_src[pos] = s;
        csr_w[pos] = dinv[s] * dinv[d];
    }
}

// ---------------- weight transpose+convert: Wt[n][k] = bf16(W[k][n]) ----------------

__global__ void wt_kernel(const float* __restrict__ W, u16* __restrict__ Wt, int K, int N) {
    int i = blockIdx.x * 256 + threadIdx.x;
    if (i >= K * N) return;
    int n = i / K, k = i - n * K;
    Wt[i] = f2bf(W[(size_t)k * N + n]);
}

// ---------------- MFMA GEMM: C[M,N] fp32 = A[M,K] fp32 @ Bt[N,K] bf16 ----------------
// A converted fp32->bf16 in-register during LDS staging. BM=128, BN=64, BK=32.
// 256 threads = 4 waves (2x2); per-wave 64x32 output = 4x2 frags of 16x16 (mfma 16x16x32).
// C stored fp32 directly with the m89-verified C/D mapping (col=lane&15, row=(lane>>4)*4+r).

__global__ __launch_bounds__(256) void gemm_bf16(const float* __restrict__ A,
                                                 const u16* __restrict__ Bt,
                                                 float* __restrict__ C,
                                                 int M, int K, int N) {
    constexpr int BM = 128, BN = 64, BK = 32;
    constexpr int AST = BK + 8;   // 40 u16 = 80B stride (16B-aligned, conflict-padded)
    __shared__ u16 As[BM * AST];

    int tid = threadIdx.x;
    int lane = tid & 63, wid = tid >> 6;
    int wr = wid >> 1, wc = wid & 1;
    int l15 = lane & 15, l4 = lane >> 4;
    int bm = blockIdx.x * BM, bn = blockIdx.y * BN;

    f32x4 acc[4][2] = {};

    int sr = tid >> 1;             // 0..127 staging row
    int sh = (tid & 1) * 16;       // float offset within BK (0 or 16)
    int arow = bm + sr;
    const float* ap = A + (size_t)arow * K + sh;
    bool aval = arow < M;

    for (int k0 = 0; k0 < K; k0 += BK) {
        float4 f0 = make_float4(0.f, 0.f, 0.f, 0.f), f1 = f0, f2 = f0, f3 = f0;
        if (aval) {
            const float4* p = (const float4*)(ap + k0);
            f0 = p[0]; f1 = p[1]; f2 = p[2]; f3 = p[3];
        }
        uint4 w0, w1;
        w0.x = pack2(f0.x, f0.y); w0.y = pack2(f0.z, f0.w);
        w0.z = pack2(f1.x, f1.y); w0.w = pack2(f1.z, f1.w);
        w1.x = pack2(f2.x, f2.y); w1.y = pack2(f2.z, f2.w);
        w1.z = pack2(f3.x, f3.y); w1.w = pack2(f3.z, f3.w);
        __syncthreads();
        *(uint4*)(&As[sr * AST + sh]) = w0;
        *(uint4*)(&As[sr * AST + sh + 8]) = w1;
        __syncthreads();

        bf16x8 bfrag[2];
#pragma unroll
        for (int nf = 0; nf < 2; ++nf) {
            int col = bn + wc * 32 + nf * 16 + l15;
            bfrag[nf] = *(const bf16x8*)(Bt + (size_t)col * K + k0 + l4 * 8);
        }
        bf16x8 afrag[4];
#pragma unroll
        for (int mf = 0; mf < 4; ++mf) {
            int row = wr * 64 + mf * 16 + l15;
            afrag[mf] = *(const bf16x8*)(&As[row * AST + l4 * 8]);
        }
#pragma unroll
        for (int mf = 0; mf < 4; ++mf)
#pragma unroll
            for (int nf = 0; nf < 2; ++nf)
                acc[mf][nf] = __builtin_amdgcn_mfma_f32_16x16x32_bf16(afrag[mf], bfrag[nf],
                                                                      acc[mf][nf], 0, 0, 0);
    }

    // direct fp32 store, C/D mapping: col = lane&15, row = (lane>>4)*4 + r
#pragma unroll
    for (int mf = 0; mf < 4; ++mf) {
#pragma unroll
        for (int nf = 0; nf < 2; ++nf) {
            int col = bn + wc * 32 + nf * 16 + l15;
#pragma unroll
            for (int r = 0; r < 4; ++r) {
                int row = bm + wr * 64 + mf * 16 + l4 * 4 + r;
                if (row < M) C[(size_t)row * N + col] = acc[mf][nf][r];
            }
        }
    }
}

// ---------------- aggregation (round-1 verbatim, fp32 H) ----------------
// out[i] = sum_e w_e*H[src_e] + dinv2[i]*H[i] + b (+epi)
// EPI: 0 = bias only, 1 = bias + l2norm, 2 = bias + residual add (Zadd)

template <int VEC, int EPI>
__global__ __launch_bounds__(256) void agg_kernel(const float* __restrict__ H,
                                                  const float* __restrict__ bias,
                                                  const float* __restrict__ Zadd,
                                                  const int* __restrict__ row_start,
                                                  const int* __restrict__ csr_src,
                                                  const float* __restrict__ csr_w,
                                                  const float* __restrict__ dinv,
                                                  float* __restrict__ out, int n) {
    const int F = VEC * 64;
    int lane = threadIdx.x & 63;
    int node = blockIdx.x * 4 + (threadIdx.x >> 6);
    if (node >= n) return;

    float acc[VEC];
    float di = dinv[node];
    float d2 = di * di;
    {
        const float* hp = H + (size_t)node * F + lane * VEC;
        if constexpr (VEC == 4) {
            float4 hv = *reinterpret_cast<const float4*>(hp);
            acc[0] = d2 * hv.x; acc[1] = d2 * hv.y; acc[2] = d2 * hv.z; acc[3] = d2 * hv.w;
        } else {
            float2 hv = *reinterpret_cast<const float2*>(hp);
            acc[0] = d2 * hv.x; acc[1] = d2 * hv.y;
        }
    }
    int beg = row_start[node], end = row_start[node + 1];
    for (int e = beg; e < end; ++e) {
        int s = csr_src[e];
        float w = csr_w[e];
        const float* hp = H + (size_t)s * F + lane * VEC;
        if constexpr (VEC == 4) {
            float4 hv = *reinterpret_cast<const float4*>(hp);
            acc[0] += w * hv.x; acc[1] += w * hv.y; acc[2] += w * hv.z; acc[3] += w * hv.w;
        } else {
            float2 hv = *reinterpret_cast<const float2*>(hp);
            acc[0] += w * hv.x; acc[1] += w * hv.y;
        }
    }
#pragma unroll
    for (int v = 0; v < VEC; ++v) acc[v] += bias[lane * VEC + v];

    if constexpr (EPI == 1) {
        float ss = 0.f;
#pragma unroll
        for (int v = 0; v < VEC; ++v) ss += acc[v] * acc[v];
#pragma unroll
        for (int off = 32; off; off >>= 1) ss += __shfl_xor(ss, off);
        float scale = 1.0f / fmaxf(sqrtf(ss), 1e-12f);
#pragma unroll
        for (int v = 0; v < VEC; ++v) acc[v] *= scale;
    } else if constexpr (EPI == 2) {
        const float* zp = Zadd + (size_t)node * F + lane * VEC;
#pragma unroll
        for (int v = 0; v < VEC; ++v) acc[v] += zp[v];
    }

    float* op = out + (size_t)node * F + lane * VEC;
    if constexpr (VEC == 4) {
        *reinterpret_cast<float4*>(op) = make_float4(acc[0], acc[1], acc[2], acc[3]);
    } else {
        *reinterpret_cast<float2*>(op) = make_float2(acc[0], acc[1]);
    }
}

// ---------------- RK4 combine (round-1 verbatim) ----------------

__global__ __launch_bounds__(256) void comb_kernel(const float4* __restrict__ X0,
                                                   const float4* __restrict__ Kv,
                                                   float4* __restrict__ ACC,
                                                   float4* __restrict__ XT,
                                                   float ca, float cx, int accInit,
                                                   int writeXT, int n4) {
    int i = blockIdx.x * 256 + threadIdx.x;
    if (i >= n4) return;
    float4 k = Kv[i];
    float4 x0 = X0[i];
    float4 a = accInit ? x0 : ACC[i];
    a.x += ca * k.x; a.y += ca * k.y; a.z += ca * k.z; a.w += ca * k.w;
    ACC[i] = a;
    if (writeXT) {
        float4 t;
        t.x = x0.x + cx * k.x; t.y = x0.y + cx * k.y;
        t.z = x0.z + cx * k.z; t.w = x0.w + cx * k.w;
        XT[i] = t;
    }
}

// ---------------- launch ----------------

extern "C" void kernel_launch(void* const* d_in, const int* in_sizes, int n_in,
                              void* d_out, int out_size, void* d_ws, size_t ws_size,
                              hipStream_t stream) {
    const float* emb = (const float*)d_in[0];
    const int* ei    = (const int*)d_in[1];
    const float* W1  = (const float*)d_in[2];
    const float* b1  = (const float*)d_in[3];
    const float* Wf1 = (const float*)d_in[4];
    const float* bf1 = (const float*)d_in[5];
    const float* Wf2 = (const float*)d_in[6];
    const float* bf2 = (const float*)d_in[7];
    const float* W2  = (const float*)d_in[8];
    const float* b2  = (const float*)d_in[9];
    float* out = (float*)d_out;

    const int N = in_sizes[0] / NINP;  // 50000
    const int E = in_sizes[1] / 2;     // 800000
    const int* esrc = ei;
    const int* edst = ei + E;

    char* p = (char*)d_ws;
    auto alloc = [&](size_t bytes) -> char* {
        char* r = p;
        p += (bytes + 255) & ~(size_t)255;
        return r;
    };
    int*   deg       = (int*)alloc((size_t)N * 4);
    float* dinv      = (float*)alloc((size_t)N * 4);
    int*   row_start = (int*)alloc((size_t)(N + 1) * 4);
    int*   cursor    = (int*)alloc((size_t)N * 4);
    int*   csr_src   = (int*)alloc((size_t)E * 4);
    float* csr_w     = (float*)alloc((size_t)E * 4);
    float* H   = (float*)alloc((size_t)N * D2 * 4);
    float* X0  = (float*)alloc((size_t)N * D2 * 4);
    float* Z1  = (float*)alloc((size_t)N * D2 * 4);  // also holds k
    float* XT  = (float*)alloc((size_t)N * D2 * 4);
    float* ACC = (float*)alloc((size_t)N * D2 * 4);
    u16*   W1t  = (u16*)alloc((size_t)NINP * D2 * 2);
    u16*   Wf1t = (u16*)alloc((size_t)D2 * D2 * 2);
    u16*   Wf2t = (u16*)alloc((size_t)D2 * D2 * 2);
    u16*   W2t  = (u16*)alloc((size_t)D2 * NINP * 2);

    const int gN = (N + 255) / 256, gE = (E + 255) / 256;
    init_deg_kernel<<<gN, 256, 0, stream>>>(deg, N);
    count_kernel<<<gE, 256, 0, stream>>>(edst, deg, E);
    dinv_kernel<<<gN, 256, 0, stream>>>(deg, dinv, N);
    scan_kernel<<<1, 1024, 0, stream>>>(deg, row_start, cursor, N);
    fill_csr_kernel<<<gE, 256, 0, stream>>>(esrc, edst, dinv, cursor, csr_src, csr_w, E);

    // weight prep (transposed bf16)
    wt_kernel<<<(NINP * D2 + 255) / 256, 256, 0, stream>>>(W1, W1t, NINP, D2);
    wt_kernel<<<(D2 * D2 + 255) / 256, 256, 0, stream>>>(Wf1, Wf1t, D2, D2);
    wt_kernel<<<(D2 * D2 + 255) / 256, 256, 0, stream>>>(Wf2, Wf2t, D2, D2);
    wt_kernel<<<(D2 * NINP + 255) / 256, 256, 0, stream>>>(W2, W2t, D2, NINP);

    auto gemm = [&](const float* A, const u16* Bt, float* C, int K, int Ncols) {
        dim3 grid((N + 127) / 128, Ncols / 64);
        gemm_bf16<<<grid, 256, 0, stream>>>(A, Bt, C, N, K, Ncols);
    };
    const int gAgg = (N + 3) / 4;
    const int n4 = N * D2 / 4;
    const int gC = (n4 + 255) / 256;

    // conv1 + l2norm -> X0
    gemm(emb, W1t, H, NINP, D2);
    agg_kernel<4, 1><<<gAgg, 256, 0, stream>>>(H, b1, nullptr, row_start, csr_src, csr_w, dinv, X0, N);

    // f(z) -> writes result into Z1
    auto fcall = [&](const float* z) {
        gemm(z, Wf1t, H, D2, D2);
        agg_kernel<4, 1><<<gAgg, 256, 0, stream>>>(H, bf1, nullptr, row_start, csr_src, csr_w, dinv, Z1, N);
        gemm(Z1, Wf2t, H, D2, D2);
        agg_kernel<4, 2><<<gAgg, 256, 0, stream>>>(H, bf2, z, row_start, csr_src, csr_w, dinv, Z1, N);
    };

    // k1
    fcall(X0);
    comb_kernel<<<gC, 256, 0, stream>>>((const float4*)X0, (const float4*)Z1, (float4*)ACC, (float4*)XT,
                                        1.f / 6.f, 0.5f, 1, 1, n4);
    // k2
    fcall(XT);
    comb_kernel<<<gC, 256, 0, stream>>>((const float4*)X0, (const float4*)Z1, (float4*)ACC, (float4*)XT,
                                        1.f / 3.f, 0.5f, 0, 1, n4);
    // k3
    fcall(XT);
    comb_kernel<<<gC, 256, 0, stream>>>((const float4*)X0, (const float4*)Z1, (float4*)ACC, (float4*)XT,
                                        1.f / 3.f, 1.0f, 0, 1, n4);
    // k4
    fcall(XT);
    comb_kernel<<<gC, 256, 0, stream>>>((const float4*)X0, (const float4*)Z1, (float4*)ACC, (float4*)XT,
                                        1.f / 6.f, 0.0f, 0, 0, n4);

    // final conv -> d_out
    gemm(ACC, W2t, H, D2, NINP);
    agg_kernel<2, 0><<<gAgg, 256, 0, stream>>>(H, b2, nullptr, row_start, csr_src, csr_w, dinv, out, N);
}

// Round 4
// 1407.174 us; speedup vs baseline: 1.6973x; 1.3823x over previous
//
#include <hip/hip_runtime.h>
#include <hip/hip_bf16.h>

static constexpr int NINP = 128;
static constexpr int D2   = 256;

using u16 = unsigned short;
using u32 = unsigned int;

typedef __attribute__((ext_vector_type(8))) __bf16 bf16x8;
typedef __attribute__((ext_vector_type(4))) float f32x4;

__device__ __forceinline__ float bf2f(u16 b) {
    union { u32 u; float f; } v;
    v.u = ((u32)b) << 16;
    return v.f;
}
__device__ __forceinline__ u16 f2bf(float f) {
    union { float f; u32 u; } v;
    v.f = f;
    u32 u = v.u + 0x7fff + ((v.u >> 16) & 1);  // RNE
    return (u16)(u >> 16);
}
__device__ __forceinline__ u32 pack2(float a, float b) {
    return (u32)f2bf(a) | ((u32)f2bf(b) << 16);
}

// ---------------- graph build (round-1 verbatim) ----------------

__global__ void init_deg_kernel(int* __restrict__ deg, int n) {
    int i = blockIdx.x * blockDim.x + threadIdx.x;
    if (i < n) deg[i] = 0;
}

__global__ void count_kernel(const int* __restrict__ dst, int* __restrict__ deg, int E) {
    int e = blockIdx.x * blockDim.x + threadIdx.x;
    if (e < E) atomicAdd(&deg[dst[e]], 1);
}

__global__ void dinv_kernel(const int* __restrict__ deg, float* __restrict__ dinv, int n) {
    int i = blockIdx.x * blockDim.x + threadIdx.x;
    if (i < n) dinv[i] = rsqrtf((float)deg[i] + 1.0f);
}

__global__ __launch_bounds__(1024) void scan_kernel(const int* __restrict__ deg,
                                                    int* __restrict__ row_start,
                                                    int* __restrict__ cursor, int n) {
    __shared__ int lds[1024];
    int t = threadIdx.x;
    int chunk = (n + 1023) >> 10;
    int beg = t * chunk, end = min(beg + chunk, n);
    int s = 0;
    for (int i = beg; i < end; ++i) s += deg[i];
    lds[t] = s;
    __syncthreads();
    for (int off = 1; off < 1024; off <<= 1) {
        int v = (t >= off) ? lds[t - off] : 0;
        __syncthreads();
        lds[t] += v;
        __syncthreads();
    }
    int run = lds[t] - s;  // exclusive prefix
    for (int i = beg; i < end; ++i) {
        row_start[i] = run;
        cursor[i] = run;
        run += deg[i];
    }
    if (t == 1023) row_start[n] = lds[1023];
}

__global__ void fill_csr_kernel(const int* __restrict__ src, const int* __restrict__ dst,
                                const float* __restrict__ dinv, int* __restrict__ cursor,
                                int* __restrict__ csr_src, float* __restrict__ csr_w, int E) {
    int e = blockIdx.x * blockDim.x + threadIdx.x;
    if (e < E) {
        int s = src[e], d = dst[e];
        int pos = atomicAdd(&cursor[d], 1);
        csr_src[pos] = s;
        csr_w[pos] = dinv[s] * dinv[d];
    }
}

// ---------------- weight transpose+convert: Wt[n][k] = bf16(W[k][n]) ----------------

__global__ void wt_kernel(const float* __restrict__ W, u16* __restrict__ Wt, int K, int N) {
    int i = blockIdx.x * 256 + threadIdx.x;
    if (i >= K * N) return;
    int n = i / K, k = i - n * K;
    Wt[i] = f2bf(W[(size_t)k * N + n]);
}

// ---------------- MFMA GEMM: C[M,N] bf16 = A[M,K] fp32 @ Bt[N,K] bf16 ----------------
// A converted fp32->bf16 in-register during LDS staging. BM=128, BN=64, BK=32.
// 256 threads = 4 waves (2x2); per-wave 64x32 output = 4x2 frags of 16x16 (mfma 16x16x32).
// C stored bf16 directly with the m89-verified C/D mapping (col=lane&15, row=(lane>>4)*4+r).

__global__ __launch_bounds__(256) void gemm_bf16(const float* __restrict__ A,
                                                 const u16* __restrict__ Bt,
                                                 u16* __restrict__ C,
                                                 int M, int K, int N) {
    constexpr int BM = 128, BN = 64, BK = 32;
    constexpr int AST = BK + 8;   // 40 u16 = 80B stride (16B-aligned, conflict-padded)
    __shared__ u16 As[BM * AST];

    int tid = threadIdx.x;
    int lane = tid & 63, wid = tid >> 6;
    int wr = wid >> 1, wc = wid & 1;
    int l15 = lane & 15, l4 = lane >> 4;
    int bm = blockIdx.x * BM, bn = blockIdx.y * BN;

    f32x4 acc[4][2] = {};

    int sr = tid >> 1;             // 0..127 staging row
    int sh = (tid & 1) * 16;       // float offset within BK (0 or 16)
    int arow = bm + sr;
    const float* ap = A + (size_t)arow * K + sh;
    bool aval = arow < M;

    for (int k0 = 0; k0 < K; k0 += BK) {
        float4 f0 = make_float4(0.f, 0.f, 0.f, 0.f), f1 = f0, f2 = f0, f3 = f0;
        if (aval) {
            const float4* p = (const float4*)(ap + k0);
            f0 = p[0]; f1 = p[1]; f2 = p[2]; f3 = p[3];
        }
        uint4 w0, w1;
        w0.x = pack2(f0.x, f0.y); w0.y = pack2(f0.z, f0.w);
        w0.z = pack2(f1.x, f1.y); w0.w = pack2(f1.z, f1.w);
        w1.x = pack2(f2.x, f2.y); w1.y = pack2(f2.z, f2.w);
        w1.z = pack2(f3.x, f3.y); w1.w = pack2(f3.z, f3.w);
        __syncthreads();
        *(uint4*)(&As[sr * AST + sh]) = w0;
        *(uint4*)(&As[sr * AST + sh + 8]) = w1;
        __syncthreads();

        bf16x8 bfrag[2];
#pragma unroll
        for (int nf = 0; nf < 2; ++nf) {
            int col = bn + wc * 32 + nf * 16 + l15;
            bfrag[nf] = *(const bf16x8*)(Bt + (size_t)col * K + k0 + l4 * 8);
        }
        bf16x8 afrag[4];
#pragma unroll
        for (int mf = 0; mf < 4; ++mf) {
            int row = wr * 64 + mf * 16 + l15;
            afrag[mf] = *(const bf16x8*)(&As[row * AST + l4 * 8]);
        }
#pragma unroll
        for (int mf = 0; mf < 4; ++mf)
#pragma unroll
            for (int nf = 0; nf < 2; ++nf)
                acc[mf][nf] = __builtin_amdgcn_mfma_f32_16x16x32_bf16(afrag[mf], bfrag[nf],
                                                                      acc[mf][nf], 0, 0, 0);
    }

    // direct bf16 store, C/D mapping: col = lane&15, row = (lane>>4)*4 + r
#pragma unroll
    for (int mf = 0; mf < 4; ++mf) {
#pragma unroll
        for (int nf = 0; nf < 2; ++nf) {
            int col = bn + wc * 32 + nf * 16 + l15;
#pragma unroll
            for (int r = 0; r < 4; ++r) {
                int row = bm + wr * 64 + mf * 16 + l4 * 4 + r;
                if (row < M) C[(size_t)row * N + col] = f2bf(acc[mf][nf][r]);
            }
        }
    }
}

// ---------------- aggregation over bf16 H ----------------
// out[i] = sum_e w_e*H[src_e] + dinv2[i]*H[i] + b (+epi)   [fp32 accumulate + fp32 out]
// EPI: 0 = bias only, 1 = bias + l2norm, 2 = bias + residual add (Zadd fp32)

template <int VEC, int EPI>
__global__ __launch_bounds__(256) void agg_kernel(const u16* __restrict__ Hb,
                                                  const float* __restrict__ bias,
                                                  const float* __restrict__ Zadd,
                                                  const int* __restrict__ row_start,
                                                  const int* __restrict__ csr_src,
                                                  const float* __restrict__ csr_w,
                                                  const float* __restrict__ dinv,
                                                  float* __restrict__ out, int n) {
    const int F = VEC * 64;
    int lane = threadIdx.x & 63;
    int node = blockIdx.x * 4 + (threadIdx.x >> 6);
    if (node >= n) return;

    float acc[VEC];
    float di = dinv[node];
    float d2 = di * di;
    int lv = lane * VEC;
    size_t base = (size_t)node * F + lv;

    // self term
    if constexpr (VEC == 4) {
        uint2 p = *(const uint2*)(Hb + base);
        acc[0] = d2 * bf2f((u16)(p.x & 0xffff));
        acc[1] = d2 * bf2f((u16)(p.x >> 16));
        acc[2] = d2 * bf2f((u16)(p.y & 0xffff));
        acc[3] = d2 * bf2f((u16)(p.y >> 16));
    } else {
        u32 p = *(const u32*)(Hb + base);
        acc[0] = d2 * bf2f((u16)(p & 0xffff));
        acc[1] = d2 * bf2f((u16)(p >> 16));
    }

    int e = row_start[node], end = row_start[node + 1];
    for (; e + 2 <= end; e += 2) {
        int s0 = csr_src[e], s1 = csr_src[e + 1];
        float w0 = csr_w[e], w1 = csr_w[e + 1];
        if constexpr (VEC == 4) {
            uint2 p0 = *(const uint2*)(Hb + (size_t)s0 * F + lv);
            uint2 p1 = *(const uint2*)(Hb + (size_t)s1 * F + lv);
            acc[0] += w0 * bf2f((u16)(p0.x & 0xffff)) + w1 * bf2f((u16)(p1.x & 0xffff));
            acc[1] += w0 * bf2f((u16)(p0.x >> 16))    + w1 * bf2f((u16)(p1.x >> 16));
            acc[2] += w0 * bf2f((u16)(p0.y & 0xffff)) + w1 * bf2f((u16)(p1.y & 0xffff));
            acc[3] += w0 * bf2f((u16)(p0.y >> 16))    + w1 * bf2f((u16)(p1.y >> 16));
        } else {
            u32 p0 = *(const u32*)(Hb + (size_t)s0 * F + lv);
            u32 p1 = *(const u32*)(Hb + (size_t)s1 * F + lv);
            acc[0] += w0 * bf2f((u16)(p0 & 0xffff)) + w1 * bf2f((u16)(p1 & 0xffff));
            acc[1] += w0 * bf2f((u16)(p0 >> 16))    + w1 * bf2f((u16)(p1 >> 16));
        }
    }
    if (e < end) {
        int s0 = csr_src[e];
        float w0 = csr_w[e];
        if constexpr (VEC == 4) {
            uint2 p0 = *(const uint2*)(Hb + (size_t)s0 * F + lv);
            acc[0] += w0 * bf2f((u16)(p0.x & 0xffff));
            acc[1] += w0 * bf2f((u16)(p0.x >> 16));
            acc[2] += w0 * bf2f((u16)(p0.y & 0xffff));
            acc[3] += w0 * bf2f((u16)(p0.y >> 16));
        } else {
            u32 p0 = *(const u32*)(Hb + (size_t)s0 * F + lv);
            acc[0] += w0 * bf2f((u16)(p0 & 0xffff));
            acc[1] += w0 * bf2f((u16)(p0 >> 16));
        }
    }

#pragma unroll
    for (int v = 0; v < VEC; ++v) acc[v] += bias[lv + v];

    if constexpr (EPI == 1) {
        float ss = 0.f;
#pragma unroll
        for (int v = 0; v < VEC; ++v) ss += acc[v] * acc[v];
#pragma unroll
        for (int off = 32; off; off >>= 1) ss += __shfl_xor(ss, off);
        float scale = 1.0f / fmaxf(sqrtf(ss), 1e-12f);
#pragma unroll
        for (int v = 0; v < VEC; ++v) acc[v] *= scale;
    } else if constexpr (EPI == 2) {
        const float* zp = Zadd + base;
#pragma unroll
        for (int v = 0; v < VEC; ++v) acc[v] += zp[v];
    }

    float* op = out + base;
    if constexpr (VEC == 4) {
        *reinterpret_cast<float4*>(op) = make_float4(acc[0], acc[1], acc[2], acc[3]);
    } else {
        *reinterpret_cast<float2*>(op) = make_float2(acc[0], acc[1]);
    }
}

// ---------------- RK4 combine (round-1 verbatim) ----------------

__global__ __launch_bounds__(256) void comb_kernel(const float4* __restrict__ X0,
                                                   const float4* __restrict__ Kv,
                                                   float4* __restrict__ ACC,
                                                   float4* __restrict__ XT,
                                                   float ca, float cx, int accInit,
                                                   int writeXT, int n4) {
    int i = blockIdx.x * 256 + threadIdx.x;
    if (i >= n4) return;
    float4 k = Kv[i];
    float4 x0 = X0[i];
    float4 a = accInit ? x0 : ACC[i];
    a.x += ca * k.x; a.y += ca * k.y; a.z += ca * k.z; a.w += ca * k.w;
    ACC[i] = a;
    if (writeXT) {
        float4 t;
        t.x = x0.x + cx * k.x; t.y = x0.y + cx * k.y;
        t.z = x0.z + cx * k.z; t.w = x0.w + cx * k.w;
        XT[i] = t;
    }
}

// ---------------- launch ----------------

extern "C" void kernel_launch(void* const* d_in, const int* in_sizes, int n_in,
                              void* d_out, int out_size, void* d_ws, size_t ws_size,
                              hipStream_t stream) {
    const float* emb = (const float*)d_in[0];
    const int* ei    = (const int*)d_in[1];
    const float* W1  = (const float*)d_in[2];
    const float* b1  = (const float*)d_in[3];
    const float* Wf1 = (const float*)d_in[4];
    const float* bf1 = (const float*)d_in[5];
    const float* Wf2 = (const float*)d_in[6];
    const float* bf2 = (const float*)d_in[7];
    const float* W2  = (const float*)d_in[8];
    const float* b2  = (const float*)d_in[9];
    float* out = (float*)d_out;

    const int N = in_sizes[0] / NINP;  // 50000
    const int E = in_sizes[1] / 2;     // 800000
    const int* esrc = ei;
    const int* edst = ei + E;

    char* p = (char*)d_ws;
    auto alloc = [&](size_t bytes) -> char* {
        char* r = p;
        p += (bytes + 255) & ~(size_t)255;
        return r;
    };
    int*   deg       = (int*)alloc((size_t)N * 4);
    float* dinv      = (float*)alloc((size_t)N * 4);
    int*   row_start = (int*)alloc((size_t)(N + 1) * 4);
    int*   cursor    = (int*)alloc((size_t)N * 4);
    int*   csr_src   = (int*)alloc((size_t)E * 4);
    float* csr_w     = (float*)alloc((size_t)E * 4);
    u16*   Hb  = (u16*)alloc((size_t)N * D2 * 2);
    float* X0  = (float*)alloc((size_t)N * D2 * 4);
    float* Z1  = (float*)alloc((size_t)N * D2 * 4);  // also holds k
    float* XT  = (float*)alloc((size_t)N * D2 * 4);
    float* ACC = (float*)alloc((size_t)N * D2 * 4);
    u16*   W1t  = (u16*)alloc((size_t)NINP * D2 * 2);
    u16*   Wf1t = (u16*)alloc((size_t)D2 * D2 * 2);
    u16*   Wf2t = (u16*)alloc((size_t)D2 * D2 * 2);
    u16*   W2t  = (u16*)alloc((size_t)D2 * NINP * 2);

    const int gN = (N + 255) / 256, gE = (E + 255) / 256;
    init_deg_kernel<<<gN, 256, 0, stream>>>(deg, N);
    count_kernel<<<gE, 256, 0, stream>>>(edst, deg, E);
    dinv_kernel<<<gN, 256, 0, stream>>>(deg, dinv, N);
    scan_kernel<<<1, 1024, 0, stream>>>(deg, row_start, cursor, N);
    fill_csr_kernel<<<gE, 256, 0, stream>>>(esrc, edst, dinv, cursor, csr_src, csr_w, E);

    // weight prep (transposed bf16)
    wt_kernel<<<(NINP * D2 + 255) / 256, 256, 0, stream>>>(W1, W1t, NINP, D2);
    wt_kernel<<<(D2 * D2 + 255) / 256, 256, 0, stream>>>(Wf1, Wf1t, D2, D2);
    wt_kernel<<<(D2 * D2 + 255) / 256, 256, 0, stream>>>(Wf2, Wf2t, D2, D2);
    wt_kernel<<<(D2 * NINP + 255) / 256, 256, 0, stream>>>(W2, W2t, D2, NINP);

    auto gemm = [&](const float* A, const u16* Bt, u16* C, int K, int Ncols) {
        dim3 grid((N + 127) / 128, Ncols / 64);
        gemm_bf16<<<grid, 256, 0, stream>>>(A, Bt, C, N, K, Ncols);
    };
    const int gAgg = (N + 3) / 4;
    const int n4 = N * D2 / 4;
    const int gC = (n4 + 255) / 256;

    // conv1 + l2norm -> X0
    gemm(emb, W1t, Hb, NINP, D2);
    agg_kernel<4, 1><<<gAgg, 256, 0, stream>>>(Hb, b1, nullptr, row_start, csr_src, csr_w, dinv, X0, N);

    // f(z) -> writes result into Z1
    auto fcall = [&](const float* z) {
        gemm(z, Wf1t, Hb, D2, D2);
        agg_kernel<4, 1><<<gAgg, 256, 0, stream>>>(Hb, bf1, nullptr, row_start, csr_src, csr_w, dinv, Z1, N);
        gemm(Z1, Wf2t, Hb, D2, D2);
        agg_kernel<4, 2><<<gAgg, 256, 0, stream>>>(Hb, bf2, z, row_start, csr_src, csr_w, dinv, Z1, N);
    };

    // k1
    fcall(X0);
    comb_kernel<<<gC, 256, 0, stream>>>((const float4*)X0, (const float4*)Z1, (float4*)ACC, (float4*)XT,
                                        1.f / 6.f, 0.5f, 1, 1, n4);
    // k2
    fcall(XT);
    comb_kernel<<<gC, 256, 0, stream>>>((const float4*)X0, (const float4*)Z1, (float4*)ACC, (float4*)XT,
                                        1.f / 3.f, 0.5f, 0, 1, n4);
    // k3
    fcall(XT);
    comb_kernel<<<gC, 256, 0, stream>>>((const float4*)X0, (const float4*)Z1, (float4*)ACC, (float4*)XT,
                                        1.f / 3.f, 1.0f, 0, 1, n4);
    // k4
    fcall(XT);
    comb_kernel<<<gC, 256, 0, stream>>>((const float4*)X0, (const float4*)Z1, (float4*)ACC, (float4*)XT,
                                        1.f / 6.f, 0.0f, 0, 0, n4);

    // final conv -> d_out
    gemm(ACC, W2t, Hb, D2, NINP);
    agg_kernel<2, 0><<<gAgg, 256, 0, stream>>>(Hb, b2, nullptr, row_start, csr_src, csr_w, dinv, out, N);
}

// Round 5
// 1188.024 us; speedup vs baseline: 2.0104x; 1.1845x over previous
//
#include <hip/hip_runtime.h>
#include <hip/hip_bf16.h>

static constexpr int NINP = 128;
static constexpr int D2   = 256;

using u16 = unsigned short;
using u32 = unsigned int;

typedef __attribute__((ext_vector_type(8))) __bf16 bf16x8;
typedef __attribute__((ext_vector_type(4))) float f32x4;

__device__ __forceinline__ float bf2f(u16 b) {
    union { u32 u; float f; } v;
    v.u = ((u32)b) << 16;
    return v.f;
}
__device__ __forceinline__ u16 f2bf(float f) {
    union { float f; u32 u; } v;
    v.f = f;
    u32 u = v.u + 0x7fff + ((v.u >> 16) & 1);  // RNE
    return (u16)(u >> 16);
}

// ---------------- graph build ----------------

__global__ void init_deg_kernel(int* __restrict__ deg, int n) {
    int i = blockIdx.x * blockDim.x + threadIdx.x;
    if (i < n) deg[i] = 0;
}

__global__ void count_kernel(const int* __restrict__ dst, int* __restrict__ deg, int E) {
    int e = blockIdx.x * blockDim.x + threadIdx.x;
    if (e < E) atomicAdd(&deg[dst[e]], 1);
}

__global__ void dinv_kernel(const int* __restrict__ deg, float* __restrict__ dinv, int n) {
    int i = blockIdx.x * blockDim.x + threadIdx.x;
    if (i < n) dinv[i] = rsqrtf((float)deg[i] + 1.0f);
}

// 3-phase parallel scan: per-block exclusive scan + block sums; top scan; add.
__global__ __launch_bounds__(256) void scan_blk_kernel(const int* __restrict__ deg,
                                                       int* __restrict__ excl,
                                                       int* __restrict__ bsum, int n) {
    __shared__ int lds[256];
    int t = threadIdx.x;
    int i = blockIdx.x * 256 + t;
    int v = (i < n) ? deg[i] : 0;
    lds[t] = v;
    __syncthreads();
    for (int off = 1; off < 256; off <<= 1) {
        int x = (t >= off) ? lds[t - off] : 0;
        __syncthreads();
        lds[t] += x;
        __syncthreads();
    }
    if (i < n) excl[i] = lds[t] - v;
    if (t == 255) bsum[blockIdx.x] = lds[255];
}

__global__ __launch_bounds__(1024) void scan_top_kernel(int* __restrict__ bsum, int nb) {
    __shared__ int lds[1024];
    int t = threadIdx.x;
    int v = (t < nb) ? bsum[t] : 0;
    lds[t] = v;
    __syncthreads();
    for (int off = 1; off < 1024; off <<= 1) {
        int x = (t >= off) ? lds[t - off] : 0;
        __syncthreads();
        lds[t] += x;
        __syncthreads();
    }
    if (t < nb) bsum[t] = lds[t] - v;  // exclusive block offsets
}

__global__ __launch_bounds__(256) void scan_add_kernel(const int* __restrict__ excl,
                                                       const int* __restrict__ bsum,
                                                       int* __restrict__ row_start,
                                                       int* __restrict__ cursor,
                                                       int n, int total) {
    int i = blockIdx.x * 256 + threadIdx.x;
    if (i < n) {
        int r = excl[i] + bsum[blockIdx.x];
        row_start[i] = r;
        cursor[i] = r;
    }
    if (i == 0) row_start[n] = total;
}

__global__ void fill_csr_kernel(const int* __restrict__ src, const int* __restrict__ dst,
                                const float* __restrict__ dinv, int* __restrict__ cursor,
                                int* __restrict__ csr_src, float* __restrict__ csr_w, int E) {
    int e = blockIdx.x * blockDim.x + threadIdx.x;
    if (e < E) {
        int s = src[e], d = dst[e];
        int pos = atomicAdd(&cursor[d], 1);
        csr_src[pos] = s;
        csr_w[pos] = dinv[s] * dinv[d];
    }
}

// ---------------- weight transpose+convert: Wt[n][k] = bf16(W[k][n]) ----------------

__global__ void wt_kernel(const float* __restrict__ W, u16* __restrict__ Wt, int K, int N) {
    int i = blockIdx.x * 256 + threadIdx.x;
    if (i >= K * N) return;
    int n = i / K, k = i - n * K;
    Wt[i] = f2bf(W[(size_t)k * N + n]);
}

// ---------------- fp32 -> bf16 convert (vector) ----------------

__global__ void cvt_kernel(const float4* __restrict__ X, uint2* __restrict__ Xb, int n4) {
    int i = blockIdx.x * 256 + threadIdx.x;
    if (i >= n4) return;
    float4 v = X[i];
    uint2 p;
    p.x = (u32)f2bf(v.x) | ((u32)f2bf(v.y) << 16);
    p.y = (u32)f2bf(v.z) | ((u32)f2bf(v.w) << 16);
    Xb[i] = p;
}

// ---------------- MFMA GEMM: C[M,N] bf16 = A[M,K] bf16 @ Bt[N,K] bf16 ----------------
// BM=128, BN=64, BK=32; 256 threads = 4 waves (2x2); per-wave 64x32 = 4x2 frags of 16x16.
// C stored bf16 directly with the verified C/D mapping (col=lane&15, row=(lane>>4)*4+r).

__global__ __launch_bounds__(256) void gemm_bf16(const u16* __restrict__ A,
                                                 const u16* __restrict__ Bt,
                                                 u16* __restrict__ C,
                                                 int M, int K, int N) {
    constexpr int BM = 128, BK = 32;
    constexpr int AST = BK + 8;   // 40 u16 = 80B stride (16B-aligned, conflict-padded)
    __shared__ u16 As[BM * AST];

    int tid = threadIdx.x;
    int lane = tid & 63, wid = tid >> 6;
    int wr = wid >> 1, wc = wid & 1;
    int l15 = lane & 15, l4 = lane >> 4;
    int bm = blockIdx.x * BM, bn = blockIdx.y * 64;

    f32x4 acc[4][2] = {};

    int sr = tid >> 1;             // 0..127 staging row
    int sh = (tid & 1) * 16;       // u16 offset within BK (0 or 16)
    int arow = bm + sr;
    const u16* ap = A + (size_t)arow * K + sh;
    bool aval = arow < M;

    for (int k0 = 0; k0 < K; k0 += BK) {
        uint4 a0 = make_uint4(0, 0, 0, 0), a1 = a0;
        if (aval) {
            const uint4* p = (const uint4*)(ap + k0);
            a0 = p[0];
            a1 = p[1];
        }
        __syncthreads();
        *(uint4*)(&As[sr * AST + sh]) = a0;
        *(uint4*)(&As[sr * AST + sh + 8]) = a1;
        __syncthreads();

        bf16x8 bfrag[2];
#pragma unroll
        for (int nf = 0; nf < 2; ++nf) {
            int col = bn + wc * 32 + nf * 16 + l15;
            bfrag[nf] = *(const bf16x8*)(Bt + (size_t)col * K + k0 + l4 * 8);
        }
        bf16x8 afrag[4];
#pragma unroll
        for (int mf = 0; mf < 4; ++mf) {
            int row = wr * 64 + mf * 16 + l15;
            afrag[mf] = *(const bf16x8*)(&As[row * AST + l4 * 8]);
        }
#pragma unroll
        for (int mf = 0; mf < 4; ++mf)
#pragma unroll
            for (int nf = 0; nf < 2; ++nf)
                acc[mf][nf] = __builtin_amdgcn_mfma_f32_16x16x32_bf16(afrag[mf], bfrag[nf],
                                                                      acc[mf][nf], 0, 0, 0);
    }

#pragma unroll
    for (int mf = 0; mf < 4; ++mf) {
#pragma unroll
        for (int nf = 0; nf < 2; ++nf) {
            int col = bn + wc * 32 + nf * 16 + l15;
#pragma unroll
            for (int r = 0; r < 4; ++r) {
                int row = bm + wr * 64 + mf * 16 + l4 * 4 + r;
                if (row < M) C[(size_t)row * N + col] = f2bf(acc[mf][nf][r]);
            }
        }
    }
}

// ---------------- aggregation over bf16 H (fp32 accumulate) ----------------
// agg[i] = sum_e w_e*H[src_e] + dinv2[i]*H[i] + bias
// EPI 0: out fp32 = agg                                  (final conv, VEC=2)
// EPI 1: l2norm(agg) -> out fp32 (opt) + outb bf16 (opt)
// EPI 3: fused RK4: k = agg + Zres; ACC' = (init?X0:ACC) + ca*k;
//        writeXT: XT = X0 + cx*k (fp32) + outb bf16(XT); else outb = bf16(ACC')

template <int VEC, int EPI>
__global__ __launch_bounds__(256) void agg_kernel(const u16* __restrict__ Hb,
                                                  const float* __restrict__ bias,
                                                  const float* __restrict__ Zres,
                                                  const float* __restrict__ X0,
                                                  float* __restrict__ ACC,
                                                  float* __restrict__ XT,
                                                  const int* __restrict__ row_start,
                                                  const int* __restrict__ csr_src,
                                                  const float* __restrict__ csr_w,
                                                  const float* __restrict__ dinv,
                                                  float* __restrict__ out,
                                                  u16* __restrict__ outb,
                                                  float ca, float cx, int accInit, int writeXT,
                                                  int n) {
    const int F = VEC * 64;
    int lane = threadIdx.x & 63;
    int node = blockIdx.x * 4 + (threadIdx.x >> 6);
    if (node >= n) return;

    float acc[VEC];
    float di = dinv[node];
    float d2 = di * di;
    int lv = lane * VEC;
    size_t base = (size_t)node * F + lv;

    // self term
    if constexpr (VEC == 4) {
        uint2 p = *(const uint2*)(Hb + base);
        acc[0] = d2 * bf2f((u16)(p.x & 0xffff));
        acc[1] = d2 * bf2f((u16)(p.x >> 16));
        acc[2] = d2 * bf2f((u16)(p.y & 0xffff));
        acc[3] = d2 * bf2f((u16)(p.y >> 16));
    } else {
        u32 p = *(const u32*)(Hb + base);
        acc[0] = d2 * bf2f((u16)(p & 0xffff));
        acc[1] = d2 * bf2f((u16)(p >> 16));
    }

    int e = row_start[node], end = row_start[node + 1];
    for (; e + 2 <= end; e += 2) {
        int s0 = csr_src[e], s1 = csr_src[e + 1];
        float w0 = csr_w[e], w1 = csr_w[e + 1];
        if constexpr (VEC == 4) {
            uint2 p0 = *(const uint2*)(Hb + (size_t)s0 * F + lv);
            uint2 p1 = *(const uint2*)(Hb + (size_t)s1 * F + lv);
            acc[0] += w0 * bf2f((u16)(p0.x & 0xffff)) + w1 * bf2f((u16)(p1.x & 0xffff));
            acc[1] += w0 * bf2f((u16)(p0.x >> 16))    + w1 * bf2f((u16)(p1.x >> 16));
            acc[2] += w0 * bf2f((u16)(p0.y & 0xffff)) + w1 * bf2f((u16)(p1.y & 0xffff));
            acc[3] += w0 * bf2f((u16)(p0.y >> 16))    + w1 * bf2f((u16)(p1.y >> 16));
        } else {
            u32 p0 = *(const u32*)(Hb + (size_t)s0 * F + lv);
            u32 p1 = *(const u32*)(Hb + (size_t)s1 * F + lv);
            acc[0] += w0 * bf2f((u16)(p0 & 0xffff)) + w1 * bf2f((u16)(p1 & 0xffff));
            acc[1] += w0 * bf2f((u16)(p0 >> 16))    + w1 * bf2f((u16)(p1 >> 16));
        }
    }
    if (e < end) {
        int s0 = csr_src[e];
        float w0 = csr_w[e];
        if constexpr (VEC == 4) {
            uint2 p0 = *(const uint2*)(Hb + (size_t)s0 * F + lv);
            acc[0] += w0 * bf2f((u16)(p0.x & 0xffff));
            acc[1] += w0 * bf2f((u16)(p0.x >> 16));
            acc[2] += w0 * bf2f((u16)(p0.y & 0xffff));
            acc[3] += w0 * bf2f((u16)(p0.y >> 16));
        } else {
            u32 p0 = *(const u32*)(Hb + (size_t)s0 * F + lv);
            acc[0] += w0 * bf2f((u16)(p0 & 0xffff));
            acc[1] += w0 * bf2f((u16)(p0 >> 16));
        }
    }

#pragma unroll
    for (int v = 0; v < VEC; ++v) acc[v] += bias[lv + v];

    if constexpr (EPI == 0) {
        *(float2*)(out + base) = make_float2(acc[0], acc[1]);
    } else if constexpr (EPI == 1) {
        float ss = 0.f;
#pragma unroll
        for (int v = 0; v < VEC; ++v) ss += acc[v] * acc[v];
#pragma unroll
        for (int off = 32; off; off >>= 1) ss += __shfl_xor(ss, off);
        float scale = 1.0f / fmaxf(sqrtf(ss), 1e-12f);
#pragma unroll
        for (int v = 0; v < VEC; ++v) acc[v] *= scale;
        if (out) *(float4*)(out + base) = make_float4(acc[0], acc[1], acc[2], acc[3]);
        if (outb) {
            uint2 p;
            p.x = (u32)f2bf(acc[0]) | ((u32)f2bf(acc[1]) << 16);
            p.y = (u32)f2bf(acc[2]) | ((u32)f2bf(acc[3]) << 16);
            *(uint2*)(outb + base) = p;
        }
    } else {  // EPI == 3, VEC == 4
        float4 z = *(const float4*)(Zres + base);
        float4 x0 = *(const float4*)(X0 + base);
        float k0 = acc[0] + z.x, k1 = acc[1] + z.y, k2 = acc[2] + z.z, k3 = acc[3] + z.w;
        float4 a = accInit ? x0 : *(const float4*)(ACC + base);
        a.x += ca * k0; a.y += ca * k1; a.z += ca * k2; a.w += ca * k3;
        *(float4*)(ACC + base) = a;
        if (writeXT) {
            float4 t;
            t.x = x0.x + cx * k0; t.y = x0.y + cx * k1;
            t.z = x0.z + cx * k2; t.w = x0.w + cx * k3;
            *(float4*)(XT + base) = t;
            uint2 p;
            p.x = (u32)f2bf(t.x) | ((u32)f2bf(t.y) << 16);
            p.y = (u32)f2bf(t.z) | ((u32)f2bf(t.w) << 16);
            *(uint2*)(outb + base) = p;
        } else {
            uint2 p;
            p.x = (u32)f2bf(a.x) | ((u32)f2bf(a.y) << 16);
            p.y = (u32)f2bf(a.z) | ((u32)f2bf(a.w) << 16);
            *(uint2*)(outb + base) = p;
        }
    }
}

// ---------------- launch ----------------

extern "C" void kernel_launch(void* const* d_in, const int* in_sizes, int n_in,
                              void* d_out, int out_size, void* d_ws, size_t ws_size,
                              hipStream_t stream) {
    const float* emb = (const float*)d_in[0];
    const int* ei    = (const int*)d_in[1];
    const float* W1  = (const float*)d_in[2];
    const float* b1  = (const float*)d_in[3];
    const float* Wf1 = (const float*)d_in[4];
    const float* bf1 = (const float*)d_in[5];
    const float* Wf2 = (const float*)d_in[6];
    const float* bf2 = (const float*)d_in[7];
    const float* W2  = (const float*)d_in[8];
    const float* b2  = (const float*)d_in[9];
    float* out = (float*)d_out;

    const int N = in_sizes[0] / NINP;  // 50000
    const int E = in_sizes[1] / 2;     // 800000
    const int* esrc = ei;
    const int* edst = ei + E;

    char* p = (char*)d_ws;
    auto alloc = [&](size_t bytes) -> char* {
        char* r = p;
        p += (bytes + 255) & ~(size_t)255;
        return r;
    };
    int*   deg       = (int*)alloc((size_t)N * 4);
    float* dinv      = (float*)alloc((size_t)N * 4);
    int*   row_start = (int*)alloc((size_t)(N + 1) * 4);
    int*   cursor    = (int*)alloc((size_t)N * 4);
    int*   sc_excl   = (int*)alloc((size_t)N * 4);
    int*   sc_bsum   = (int*)alloc((size_t)1024 * 4);
    int*   csr_src   = (int*)alloc((size_t)E * 4);
    float* csr_w     = (float*)alloc((size_t)E * 4);
    u16*   Hb   = (u16*)alloc((size_t)N * D2 * 2);
    float* X0   = (float*)alloc((size_t)N * D2 * 4);
    float* XT   = (float*)alloc((size_t)N * D2 * 4);
    float* ACC  = (float*)alloc((size_t)N * D2 * 4);
    u16*   X0b  = (u16*)alloc((size_t)N * D2 * 2);   // aliased by ACCb (disjoint lifetime)
    u16*   XTb  = (u16*)alloc((size_t)N * D2 * 2);   // aliased by embb (disjoint lifetime)
    u16*   Z1b  = (u16*)alloc((size_t)N * D2 * 2);
    u16*   W1t  = (u16*)alloc((size_t)NINP * D2 * 2);
    u16*   Wf1t = (u16*)alloc((size_t)D2 * D2 * 2);
    u16*   Wf2t = (u16*)alloc((size_t)D2 * D2 * 2);
    u16*   W2t  = (u16*)alloc((size_t)D2 * NINP * 2);
    u16*   ACCb = X0b;
    u16*   embb = XTb;

    const int gN = (N + 255) / 256, gE = (E + 255) / 256;
    init_deg_kernel<<<gN, 256, 0, stream>>>(deg, N);
    count_kernel<<<gE, 256, 0, stream>>>(edst, deg, E);
    dinv_kernel<<<gN, 256, 0, stream>>>(deg, dinv, N);
    scan_blk_kernel<<<gN, 256, 0, stream>>>(deg, sc_excl, sc_bsum, N);
    scan_top_kernel<<<1, 1024, 0, stream>>>(sc_bsum, gN);
    scan_add_kernel<<<gN, 256, 0, stream>>>(sc_excl, sc_bsum, row_start, cursor, N, E);
    fill_csr_kernel<<<gE, 256, 0, stream>>>(esrc, edst, dinv, cursor, csr_src, csr_w, E);

    // weight prep (transposed bf16) + emb convert
    wt_kernel<<<(NINP * D2 + 255) / 256, 256, 0, stream>>>(W1, W1t, NINP, D2);
    wt_kernel<<<(D2 * D2 + 255) / 256, 256, 0, stream>>>(Wf1, Wf1t, D2, D2);
    wt_kernel<<<(D2 * D2 + 255) / 256, 256, 0, stream>>>(Wf2, Wf2t, D2, D2);
    wt_kernel<<<(D2 * NINP + 255) / 256, 256, 0, stream>>>(W2, W2t, D2, NINP);
    cvt_kernel<<<(N * NINP / 4 + 255) / 256, 256, 0, stream>>>((const float4*)emb, (uint2*)embb,
                                                               N * NINP / 4);

    auto gemm = [&](const u16* A, const u16* Bt, u16* C, int K, int Ncols) {
        dim3 grid((N + 127) / 128, Ncols / 64);
        gemm_bf16<<<grid, 256, 0, stream>>>(A, Bt, C, N, K, Ncols);
    };
    const int gAgg = (N + 3) / 4;

    // conv1 + l2norm -> X0 (fp32) + X0b (bf16)
    gemm(embb, W1t, Hb, NINP, D2);
    agg_kernel<4, 1><<<gAgg, 256, 0, stream>>>(Hb, b1, nullptr, nullptr, nullptr, nullptr,
                                               row_start, csr_src, csr_w, dinv, X0, X0b,
                                               0.f, 0.f, 0, 0, N);

    // f(z) + fused RK4 stage
    auto fstage = [&](const u16* zb, const float* zres, float ca, float cx, int accInit,
                      int writeXT, u16* outb) {
        gemm(zb, Wf1t, Hb, D2, D2);
        agg_kernel<4, 1><<<gAgg, 256, 0, stream>>>(Hb, bf1, nullptr, nullptr, nullptr, nullptr,
                                                   row_start, csr_src, csr_w, dinv, nullptr, Z1b,
                                                   0.f, 0.f, 0, 0, N);
        gemm(Z1b, Wf2t, Hb, D2, D2);
        agg_kernel<4, 3><<<gAgg, 256, 0, stream>>>(Hb, bf2, zres, X0, ACC, XT,
                                                   row_start, csr_src, csr_w, dinv, nullptr, outb,
                                                   ca, cx, accInit, writeXT, N);
    };

    fstage(X0b, X0, 1.f / 6.f, 0.5f, 1, 1, XTb);  // k1
    fstage(XTb, XT, 1.f / 3.f, 0.5f, 0, 1, XTb);  // k2
    fstage(XTb, XT, 1.f / 3.f, 1.0f, 0, 1, XTb);  // k3
    fstage(XTb, XT, 1.f / 6.f, 0.0f, 0, 0, ACCb); // k4 -> ACC (fp32) + ACCb (bf16)

    // final conv -> d_out (fp32)
    gemm(ACCb, W2t, Hb, D2, NINP);
    agg_kernel<2, 0><<<gAgg, 256, 0, stream>>>(Hb, b2, nullptr, nullptr, nullptr, nullptr,
                                               row_start, csr_src, csr_w, dinv, out, nullptr,
                                               0.f, 0.f, 0, 0, N);
}

// Round 6
// 1055.388 us; speedup vs baseline: 2.2630x; 1.1257x over previous
//
#include <hip/hip_runtime.h>
#include <hip/hip_bf16.h>

static constexpr int NINP = 128;
static constexpr int D2   = 256;

using u16 = unsigned short;
using u32 = unsigned int;

typedef __attribute__((ext_vector_type(8))) __bf16 bf16x8;
typedef __attribute__((ext_vector_type(4))) float f32x4;

__device__ __forceinline__ float bf2f(u16 b) {
    union { u32 u; float f; } v;
    v.u = ((u32)b) << 16;
    return v.f;
}
__device__ __forceinline__ u16 f2bf(float f) {
    union { float f; u32 u; } v;
    v.f = f;
    u32 u = v.u + 0x7fff + ((v.u >> 16) & 1);  // RNE
    return (u16)(u >> 16);
}

// ---------------- graph build ----------------

__global__ void init_deg_kernel(int* __restrict__ deg, int n) {
    int i = blockIdx.x * blockDim.x + threadIdx.x;
    if (i < n) deg[i] = 0;
}

__global__ void count_kernel(const int* __restrict__ dst, int* __restrict__ deg, int E) {
    int e = blockIdx.x * blockDim.x + threadIdx.x;
    if (e < E) atomicAdd(&deg[dst[e]], 1);
}

__global__ void dinv_kernel(const int* __restrict__ deg, float* __restrict__ dinv, int n) {
    int i = blockIdx.x * blockDim.x + threadIdx.x;
    if (i < n) dinv[i] = rsqrtf((float)deg[i] + 1.0f);
}

// 3-phase parallel scan: per-block exclusive scan + block sums; top scan; add.
__global__ __launch_bounds__(256) void scan_blk_kernel(const int* __restrict__ deg,
                                                       int* __restrict__ excl,
                                                       int* __restrict__ bsum, int n) {
    __shared__ int lds[256];
    int t = threadIdx.x;
    int i = blockIdx.x * 256 + t;
    int v = (i < n) ? deg[i] : 0;
    lds[t] = v;
    __syncthreads();
    for (int off = 1; off < 256; off <<= 1) {
        int x = (t >= off) ? lds[t - off] : 0;
        __syncthreads();
        lds[t] += x;
        __syncthreads();
    }
    if (i < n) excl[i] = lds[t] - v;
    if (t == 255) bsum[blockIdx.x] = lds[255];
}

__global__ __launch_bounds__(1024) void scan_top_kernel(int* __restrict__ bsum, int nb) {
    __shared__ int lds[1024];
    int t = threadIdx.x;
    int v = (t < nb) ? bsum[t] : 0;
    lds[t] = v;
    __syncthreads();
    for (int off = 1; off < 1024; off <<= 1) {
        int x = (t >= off) ? lds[t - off] : 0;
        __syncthreads();
        lds[t] += x;
        __syncthreads();
    }
    if (t < nb) bsum[t] = lds[t] - v;  // exclusive block offsets
}

__global__ __launch_bounds__(256) void scan_add_kernel(const int* __restrict__ excl,
                                                       const int* __restrict__ bsum,
                                                       int* __restrict__ row_start,
                                                       int* __restrict__ cursor,
                                                       int n, int total) {
    int i = blockIdx.x * 256 + threadIdx.x;
    if (i < n) {
        int r = excl[i] + bsum[blockIdx.x];
        row_start[i] = r;
        cursor[i] = r;
    }
    if (i == 0) row_start[n] = total;
}

__global__ void fill_csr_kernel(const int* __restrict__ src, const int* __restrict__ dst,
                                const float* __restrict__ dinv, int* __restrict__ cursor,
                                int* __restrict__ csr_src, float* __restrict__ csr_w, int E) {
    int e = blockIdx.x * blockDim.x + threadIdx.x;
    if (e < E) {
        int s = src[e], d = dst[e];
        int pos = atomicAdd(&cursor[d], 1);
        csr_src[pos] = s;
        csr_w[pos] = dinv[s] * dinv[d];
    }
}

// ---------------- weight transpose+convert: Wt[n][k] = bf16(W[k][n]) ----------------

__global__ void wt_kernel(const float* __restrict__ W, u16* __restrict__ Wt, int K, int N) {
    int i = blockIdx.x * 256 + threadIdx.x;
    if (i >= K * N) return;
    int n = i / K, k = i - n * K;
    Wt[i] = f2bf(W[(size_t)k * N + n]);
}

// ---------------- fp32 -> bf16 convert (vector) ----------------

__global__ void cvt_kernel(const float4* __restrict__ X, uint2* __restrict__ Xb, int n4) {
    int i = blockIdx.x * 256 + threadIdx.x;
    if (i >= n4) return;
    float4 v = X[i];
    uint2 p;
    p.x = (u32)f2bf(v.x) | ((u32)f2bf(v.y) << 16);
    p.y = (u32)f2bf(v.z) | ((u32)f2bf(v.w) << 16);
    Xb[i] = p;
}

// ---------------- MFMA GEMM: C[M,N] bf16 = A[M,K] bf16 @ Bt[N,K] bf16 ----------------
// BM=128, BN=128, BK=32; 256 threads = 4 waves (2x2); per-wave 64x64 = 4x4 frags of 16x16.
// A staged in LDS with reg-prefetch of the next tile; B frags direct from global (L2-resident).
// C stored bf16 directly with the verified C/D mapping (col=lane&15, row=(lane>>4)*4+r).

__global__ __launch_bounds__(256, 2) void gemm_bf16(const u16* __restrict__ A,
                                                    const u16* __restrict__ Bt,
                                                    u16* __restrict__ C,
                                                    int M, int K, int N) {
    constexpr int BM = 128, BK = 32;
    constexpr int AST = BK + 8;   // 40 u16 = 80B stride (16B-aligned, conflict-padded)
    __shared__ u16 As[BM * AST];

    int tid = threadIdx.x;
    int lane = tid & 63, wid = tid >> 6;
    int wr = wid >> 1, wc = wid & 1;
    int l15 = lane & 15, l4 = lane >> 4;
    int bm = blockIdx.x * BM, bn = blockIdx.y * 128;

    f32x4 acc[4][4] = {};

    int sr = tid >> 1;             // 0..127 staging row
    int sh = (tid & 1) * 16;       // u16 offset within BK (0 or 16)
    int arow = bm + sr;
    const u16* ap = A + (size_t)arow * K + sh;
    bool aval = arow < M;

    uint4 a0 = make_uint4(0, 0, 0, 0), a1 = a0;
    if (aval) {
        const uint4* p = (const uint4*)ap;
        a0 = p[0];
        a1 = p[1];
    }

    for (int k0 = 0; k0 < K; k0 += BK) {
        __syncthreads();
        *(uint4*)(&As[sr * AST + sh]) = a0;
        *(uint4*)(&As[sr * AST + sh + 8]) = a1;
        __syncthreads();

        if (k0 + BK < K && aval) {  // prefetch next A tile into regs
            const uint4* p = (const uint4*)(ap + k0 + BK);
            a0 = p[0];
            a1 = p[1];
        }

        bf16x8 bfrag[4];
#pragma unroll
        for (int nf = 0; nf < 4; ++nf) {
            int col = bn + wc * 64 + nf * 16 + l15;
            bfrag[nf] = *(const bf16x8*)(Bt + (size_t)col * K + k0 + l4 * 8);
        }
        bf16x8 afrag[4];
#pragma unroll
        for (int mf = 0; mf < 4; ++mf) {
            int row = wr * 64 + mf * 16 + l15;
            afrag[mf] = *(const bf16x8*)(&As[row * AST + l4 * 8]);
        }
#pragma unroll
        for (int mf = 0; mf < 4; ++mf)
#pragma unroll
            for (int nf = 0; nf < 4; ++nf)
                acc[mf][nf] = __builtin_amdgcn_mfma_f32_16x16x32_bf16(afrag[mf], bfrag[nf],
                                                                      acc[mf][nf], 0, 0, 0);
    }

#pragma unroll
    for (int mf = 0; mf < 4; ++mf) {
#pragma unroll
        for (int nf = 0; nf < 4; ++nf) {
            int col = bn + wc * 64 + nf * 16 + l15;
#pragma unroll
            for (int r = 0; r < 4; ++r) {
                int row = bm + wr * 64 + mf * 16 + l4 * 4 + r;
                if (row < M) C[(size_t)row * N + col] = f2bf(acc[mf][nf][r]);
            }
        }
    }
}

// ---------------- aggregation over bf16 H (fp32 accumulate) ----------------
// agg[i] = sum_e w_e*H[src_e] + dinv2[i]*H[i] + bias
// EPI 0: out fp32 = agg                                  (final conv, VEC=2)
// EPI 1: l2norm(agg) -> out fp32 (opt) + outb bf16 (opt)
// EPI 3: fused RK4: k = agg + Zb(bf16); writeXT: ACC' = (init?X0:ACC)+ca*k, XTb = bf16(X0+cx*k)
//        else: ACC' = ACC + ca*k, outb = bf16(ACC')   [no fp32 XT tensor at all]

template <int VEC, int EPI>
__global__ __launch_bounds__(256) void agg_kernel(const u16* __restrict__ Hb,
                                                  const float* __restrict__ bias,
                                                  const u16* __restrict__ Zb,
                                                  const float* __restrict__ X0,
                                                  float* __restrict__ ACC,
                                                  const int* __restrict__ row_start,
                                                  const int* __restrict__ csr_src,
                                                  const float* __restrict__ csr_w,
                                                  const float* __restrict__ dinv,
                                                  float* __restrict__ out,
                                                  u16* __restrict__ outb,
                                                  float ca, float cx, int accInit, int writeXT,
                                                  int n) {
    const int F = VEC * 64;
    int lane = threadIdx.x & 63;
    int node = blockIdx.x * 4 + (threadIdx.x >> 6);
    if (node >= n) return;

    float acc[VEC];
    float di = dinv[node];
    float d2 = di * di;
    int lv = lane * VEC;
    size_t base = (size_t)node * F + lv;

    // self term
    if constexpr (VEC == 4) {
        uint2 p = *(const uint2*)(Hb + base);
        acc[0] = d2 * bf2f((u16)(p.x & 0xffff));
        acc[1] = d2 * bf2f((u16)(p.x >> 16));
        acc[2] = d2 * bf2f((u16)(p.y & 0xffff));
        acc[3] = d2 * bf2f((u16)(p.y >> 16));
    } else {
        u32 p = *(const u32*)(Hb + base);
        acc[0] = d2 * bf2f((u16)(p & 0xffff));
        acc[1] = d2 * bf2f((u16)(p >> 16));
    }

    int e = row_start[node], end = row_start[node + 1];
    if constexpr (VEC == 4) {
        for (; e + 4 <= end; e += 4) {
            int s0 = csr_src[e], s1 = csr_src[e + 1], s2 = csr_src[e + 2], s3 = csr_src[e + 3];
            float w0 = csr_w[e], w1 = csr_w[e + 1], w2 = csr_w[e + 2], w3 = csr_w[e + 3];
            uint2 p0 = *(const uint2*)(Hb + (size_t)s0 * F + lv);
            uint2 p1 = *(const uint2*)(Hb + (size_t)s1 * F + lv);
            uint2 p2 = *(const uint2*)(Hb + (size_t)s2 * F + lv);
            uint2 p3 = *(const uint2*)(Hb + (size_t)s3 * F + lv);
            acc[0] += w0 * bf2f((u16)(p0.x & 0xffff)) + w1 * bf2f((u16)(p1.x & 0xffff))
                    + w2 * bf2f((u16)(p2.x & 0xffff)) + w3 * bf2f((u16)(p3.x & 0xffff));
            acc[1] += w0 * bf2f((u16)(p0.x >> 16)) + w1 * bf2f((u16)(p1.x >> 16))
                    + w2 * bf2f((u16)(p2.x >> 16)) + w3 * bf2f((u16)(p3.x >> 16));
            acc[2] += w0 * bf2f((u16)(p0.y & 0xffff)) + w1 * bf2f((u16)(p1.y & 0xffff))
                    + w2 * bf2f((u16)(p2.y & 0xffff)) + w3 * bf2f((u16)(p3.y & 0xffff));
            acc[3] += w0 * bf2f((u16)(p0.y >> 16)) + w1 * bf2f((u16)(p1.y >> 16))
                    + w2 * bf2f((u16)(p2.y >> 16)) + w3 * bf2f((u16)(p3.y >> 16));
        }
        for (; e < end; ++e) {
            int s0 = csr_src[e];
            float w0 = csr_w[e];
            uint2 p0 = *(const uint2*)(Hb + (size_t)s0 * F + lv);
            acc[0] += w0 * bf2f((u16)(p0.x & 0xffff));
            acc[1] += w0 * bf2f((u16)(p0.x >> 16));
            acc[2] += w0 * bf2f((u16)(p0.y & 0xffff));
            acc[3] += w0 * bf2f((u16)(p0.y >> 16));
        }
    } else {
        for (; e + 2 <= end; e += 2) {
            int s0 = csr_src[e], s1 = csr_src[e + 1];
            float w0 = csr_w[e], w1 = csr_w[e + 1];
            u32 p0 = *(const u32*)(Hb + (size_t)s0 * F + lv);
            u32 p1 = *(const u32*)(Hb + (size_t)s1 * F + lv);
            acc[0] += w0 * bf2f((u16)(p0 & 0xffff)) + w1 * bf2f((u16)(p1 & 0xffff));
            acc[1] += w0 * bf2f((u16)(p0 >> 16))    + w1 * bf2f((u16)(p1 >> 16));
        }
        if (e < end) {
            int s0 = csr_src[e];
            float w0 = csr_w[e];
            u32 p0 = *(const u32*)(Hb + (size_t)s0 * F + lv);
            acc[0] += w0 * bf2f((u16)(p0 & 0xffff));
            acc[1] += w0 * bf2f((u16)(p0 >> 16));
        }
    }

#pragma unroll
    for (int v = 0; v < VEC; ++v) acc[v] += bias[lv + v];

    if constexpr (EPI == 0) {
        *(float2*)(out + base) = make_float2(acc[0], acc[1]);
    } else if constexpr (EPI == 1) {
        float ss = 0.f;
#pragma unroll
        for (int v = 0; v < VEC; ++v) ss += acc[v] * acc[v];
#pragma unroll
        for (int off = 32; off; off >>= 1) ss += __shfl_xor(ss, off);
        float scale = 1.0f / fmaxf(sqrtf(ss), 1e-12f);
#pragma unroll
        for (int v = 0; v < VEC; ++v) acc[v] *= scale;
        if (out) *(float4*)(out + base) = make_float4(acc[0], acc[1], acc[2], acc[3]);
        if (outb) {
            uint2 p;
            p.x = (u32)f2bf(acc[0]) | ((u32)f2bf(acc[1]) << 16);
            p.y = (u32)f2bf(acc[2]) | ((u32)f2bf(acc[3]) << 16);
            *(uint2*)(outb + base) = p;
        }
    } else {  // EPI == 3, VEC == 4
        uint2 zp = *(const uint2*)(Zb + base);
        float k0 = acc[0] + bf2f((u16)(zp.x & 0xffff));
        float k1 = acc[1] + bf2f((u16)(zp.x >> 16));
        float k2 = acc[2] + bf2f((u16)(zp.y & 0xffff));
        float k3 = acc[3] + bf2f((u16)(zp.y >> 16));
        if (writeXT) {
            float4 x0 = *(const float4*)(X0 + base);
            float4 a = accInit ? x0 : *(const float4*)(ACC + base);
            a.x += ca * k0; a.y += ca * k1; a.z += ca * k2; a.w += ca * k3;
            *(float4*)(ACC + base) = a;
            float tx = x0.x + cx * k0, ty = x0.y + cx * k1;
            float tz = x0.z + cx * k2, tw = x0.w + cx * k3;
            uint2 p;
            p.x = (u32)f2bf(tx) | ((u32)f2bf(ty) << 16);
            p.y = (u32)f2bf(tz) | ((u32)f2bf(tw) << 16);
            *(uint2*)(outb + base) = p;
        } else {
            float4 a = *(const float4*)(ACC + base);
            a.x += ca * k0; a.y += ca * k1; a.z += ca * k2; a.w += ca * k3;
            *(float4*)(ACC + base) = a;
            uint2 p;
            p.x = (u32)f2bf(a.x) | ((u32)f2bf(a.y) << 16);
            p.y = (u32)f2bf(a.z) | ((u32)f2bf(a.w) << 16);
            *(uint2*)(outb + base) = p;
        }
    }
}

// ---------------- launch ----------------

extern "C" void kernel_launch(void* const* d_in, const int* in_sizes, int n_in,
                              void* d_out, int out_size, void* d_ws, size_t ws_size,
                              hipStream_t stream) {
    const float* emb = (const float*)d_in[0];
    const int* ei    = (const int*)d_in[1];
    const float* W1  = (const float*)d_in[2];
    const float* b1  = (const float*)d_in[3];
    const float* Wf1 = (const float*)d_in[4];
    const float* bf1 = (const float*)d_in[5];
    const float* Wf2 = (const float*)d_in[6];
    const float* bf2 = (const float*)d_in[7];
    const float* W2  = (const float*)d_in[8];
    const float* b2  = (const float*)d_in[9];
    float* out = (float*)d_out;

    const int N = in_sizes[0] / NINP;  // 50000
    const int E = in_sizes[1] / 2;     // 800000
    const int* esrc = ei;
    const int* edst = ei + E;

    char* p = (char*)d_ws;
    auto alloc = [&](size_t bytes) -> char* {
        char* r = p;
        p += (bytes + 255) & ~(size_t)255;
        return r;
    };
    int*   deg       = (int*)alloc((size_t)N * 4);
    float* dinv      = (float*)alloc((size_t)N * 4);
    int*   row_start = (int*)alloc((size_t)(N + 1) * 4);
    int*   cursor    = (int*)alloc((size_t)N * 4);
    int*   sc_excl   = (int*)alloc((size_t)N * 4);
    int*   sc_bsum   = (int*)alloc((size_t)1024 * 4);
    int*   csr_src   = (int*)alloc((size_t)E * 4);
    float* csr_w     = (float*)alloc((size_t)E * 4);
    u16*   Hb   = (u16*)alloc((size_t)N * D2 * 2);
    float* X0   = (float*)alloc((size_t)N * D2 * 4);
    float* ACC  = (float*)alloc((size_t)N * D2 * 4);
    u16*   X0b  = (u16*)alloc((size_t)N * D2 * 2);   // aliased by ACCb (disjoint lifetime)
    u16*   XTb  = (u16*)alloc((size_t)N * D2 * 2);   // aliased by embb (disjoint lifetime)
    u16*   Z1b  = (u16*)alloc((size_t)N * D2 * 2);
    u16*   W1t  = (u16*)alloc((size_t)NINP * D2 * 2);
    u16*   Wf1t = (u16*)alloc((size_t)D2 * D2 * 2);
    u16*   Wf2t = (u16*)alloc((size_t)D2 * D2 * 2);
    u16*   W2t  = (u16*)alloc((size_t)D2 * NINP * 2);
    u16*   ACCb = X0b;
    u16*   embb = XTb;

    const int gN = (N + 255) / 256, gE = (E + 255) / 256;
    init_deg_kernel<<<gN, 256, 0, stream>>>(deg, N);
    count_kernel<<<gE, 256, 0, stream>>>(edst, deg, E);
    dinv_kernel<<<gN, 256, 0, stream>>>(deg, dinv, N);
    scan_blk_kernel<<<gN, 256, 0, stream>>>(deg, sc_excl, sc_bsum, N);
    scan_top_kernel<<<1, 1024, 0, stream>>>(sc_bsum, gN);
    scan_add_kernel<<<gN, 256, 0, stream>>>(sc_excl, sc_bsum, row_start, cursor, N, E);
    fill_csr_kernel<<<gE, 256, 0, stream>>>(esrc, edst, dinv, cursor, csr_src, csr_w, E);

    // weight prep (transposed bf16) + emb convert
    wt_kernel<<<(NINP * D2 + 255) / 256, 256, 0, stream>>>(W1, W1t, NINP, D2);
    wt_kernel<<<(D2 * D2 + 255) / 256, 256, 0, stream>>>(Wf1, Wf1t, D2, D2);
    wt_kernel<<<(D2 * D2 + 255) / 256, 256, 0, stream>>>(Wf2, Wf2t, D2, D2);
    wt_kernel<<<(D2 * NINP + 255) / 256, 256, 0, stream>>>(W2, W2t, D2, NINP);
    cvt_kernel<<<(N * NINP / 4 + 255) / 256, 256, 0, stream>>>((const float4*)emb, (uint2*)embb,
                                                               N * NINP / 4);

    auto gemm = [&](const u16* A, const u16* Bt, u16* C, int K, int Ncols) {
        dim3 grid((N + 127) / 128, Ncols / 128);
        gemm_bf16<<<grid, 256, 0, stream>>>(A, Bt, C, N, K, Ncols);
    };
    const int gAgg = (N + 3) / 4;

    // conv1 + l2norm -> X0 (fp32) + X0b (bf16)
    gemm(embb, W1t, Hb, NINP, D2);
    agg_kernel<4, 1><<<gAgg, 256, 0, stream>>>(Hb, b1, nullptr, nullptr, nullptr,
                                               row_start, csr_src, csr_w, dinv, X0, X0b,
                                               0.f, 0.f, 0, 0, N);

    // f(z) + fused RK4 stage (residual Zb read as bf16; XT exists only as bf16)
    auto fstage = [&](const u16* zb, const u16* zres, float ca, float cx, int accInit,
                      int writeXT, u16* outb) {
        gemm(zb, Wf1t, Hb, D2, D2);
        agg_kernel<4, 1><<<gAgg, 256, 0, stream>>>(Hb, bf1, nullptr, nullptr, nullptr,
                                                   row_start, csr_src, csr_w, dinv, nullptr, Z1b,
                                                   0.f, 0.f, 0, 0, N);
        gemm(Z1b, Wf2t, Hb, D2, D2);
        agg_kernel<4, 3><<<gAgg, 256, 0, stream>>>(Hb, bf2, zres, X0, ACC,
                                                   row_start, csr_src, csr_w, dinv, nullptr, outb,
                                                   ca, cx, accInit, writeXT, N);
    };

    fstage(X0b, X0b, 1.f / 6.f, 0.5f, 1, 1, XTb);  // k1
    fstage(XTb, XTb, 1.f / 3.f, 0.5f, 0, 1, XTb);  // k2
    fstage(XTb, XTb, 1.f / 3.f, 1.0f, 0, 1, XTb);  // k3
    fstage(XTb, XTb, 1.f / 6.f, 0.0f, 0, 0, ACCb); // k4 -> ACC (fp32) + ACCb (bf16)

    // final conv -> d_out (fp32)
    gemm(ACCb, W2t, Hb, D2, NINP);
    agg_kernel<2, 0><<<gAgg, 256, 0, stream>>>(Hb, b2, nullptr, nullptr, nullptr,
                                               row_start, csr_src, csr_w, dinv, out, nullptr,
                                               0.f, 0.f, 0, 0, N);
}